// Round 1
// baseline (4746.838 us; speedup 1.0000x reference)
//
#include <hip/hip_runtime.h>
#include <hip/hip_bf16.h>

#define CC 96

// ---------------- Kernel 1: windowed MHA (RMSNorm fused) + residual ----------------
// grid = 4096 windows, block = 256 (4 waves). LDS ~62KB -> 2 blocks/CU.
__global__ __launch_bounds__(256) void attn_kernel(
    const float* __restrict__ x,
    const float* __restrict__ norm_w,
    const float* __restrict__ qkv_w,
    const float* __restrict__ qkv_b,
    const float* __restrict__ proj_w,
    const float* __restrict__ proj_b,
    const float* __restrict__ bias_table,
    float* __restrict__ out)
{
  extern __shared__ float lds[];
  float* xr   = lds;             // [64][97] window tokens (normalized in place)
  float* qs   = xr + 64*97;      // [64][25] per-head q  (later reused for o_h)
  float* ks   = qs + 64*25;      // [64][25]
  float* vs   = ks + 64*25;      // [64][25]
  float* sc   = vs + 64*25;      // [64][65] scores / probs
  float* scl  = sc + 64*65;      // [64] rms scale
  float* btab = scl + 64;        // [225]

  const int wid = blockIdx.x;
  const int b  = wid >> 10;
  const int wy = (wid >> 5) & 31;
  const int wx = wid & 31;
  const int t  = threadIdx.x;
  const int y0 = wy*8, x0 = wx*8;

  for (int i = t; i < 225; i += 256) btab[i] = bias_table[i];

  // ---- load window: token n = ty*8+tx, channel c ----
  for (int e = t; e < 1536; e += 256) {
    const int c   = e >> 4;
    const int q4  = e & 15;
    const int ty  = q4 >> 1;
    const int tx0 = (q4 & 1) << 2;
    const float4 v = *(const float4*)(x + (size_t)(b*CC+c)*65536 + (size_t)(y0+ty)*256 + x0 + tx0);
    const int n = ty*8 + tx0;
    xr[(n+0)*97 + c] = v.x;
    xr[(n+1)*97 + c] = v.y;
    xr[(n+2)*97 + c] = v.z;
    xr[(n+3)*97 + c] = v.w;
  }
  __syncthreads();

  // ---- RMS scale per token ----
  if (t < 64) {
    float ss = 0.f;
    #pragma unroll
    for (int c = 0; c < 96; c++) { const float u = xr[t*97+c]; ss += u*u; }
    scl[t] = rsqrtf(ss * (1.0f/96.0f) + 1e-6f);
  }
  __syncthreads();
  // normalize in place: xn = x * rsqrt * norm_w[c]
  for (int e = t; e < 6144; e += 256) {
    const int nn = e / 96, c = e - nn*96;
    xr[nn*97+c] *= scl[nn] * norm_w[c];
  }
  __syncthreads();

  const int n = t & 63;   // token for this thread
  const int g = t >> 6;   // wave group 0..3
  float pacc[24];         // proj accumulator: output channels g*24..g*24+23 of token n
  #pragma unroll
  for (int i = 0; i < 24; i++) pacc[i] = 0.f;

  for (int h = 0; h < 4; h++) {
    // ---- QKV for head h: group g computes j = g*18 .. g*18+17 of 72 outputs ----
    {
      float acc[18];
      #pragma unroll
      for (int i = 0; i < 18; i++) acc[i] = 0.f;
      for (int c = 0; c < 96; c++) {
        const float xv = xr[n*97+c];
        #pragma unroll
        for (int i = 0; i < 18; i++) {
          const int j = g*18 + i;
          const int s = j / 24, dd = j - s*24;
          acc[i] += xv * qkv_w[(s*96 + h*24 + dd)*96 + c];   // wave-uniform -> s_load
        }
      }
      #pragma unroll
      for (int i = 0; i < 18; i++) {
        const int j = g*18 + i;
        const int s = j / 24, dd = j - s*24;
        const float val = acc[i] + qkv_b[s*96 + h*24 + dd];
        if (s == 0)      qs[n*25+dd] = val;
        else if (s == 1) ks[n*25+dd] = val;
        else             vs[n*25+dd] = val;
      }
    }
    __syncthreads();

    // ---- scores: s[n][m] for m in g*16..g*16+15 ----
    {
      float acc[16];
      #pragma unroll
      for (int i = 0; i < 16; i++) acc[i] = 0.f;
      for (int d = 0; d < 24; d++) {
        const float qv = qs[n*25+d];
        #pragma unroll
        for (int mi = 0; mi < 16; mi++)
          acc[mi] += qv * ks[(g*16+mi)*25 + d];   // m uniform across wave -> broadcast
      }
      const int ny = n >> 3, nx = n & 7;
      #pragma unroll
      for (int mi = 0; mi < 16; mi++) {
        const int m = g*16 + mi;
        const int my = m >> 3, mx = m & 7;
        sc[n*65+m] = acc[mi] * 0.20412414523193154f   // 1/sqrt(24)
                   + btab[(ny-my+7)*15 + (nx-mx+7)];
      }
    }
    __syncthreads();

    // ---- softmax rows (one thread per row) ----
    if (t < 64) {
      float mx = -1e30f;
      for (int m = 0; m < 64; m++) mx = fmaxf(mx, sc[t*65+m]);
      float sum = 0.f;
      for (int m = 0; m < 64; m++) { const float p = __expf(sc[t*65+m]-mx); sc[t*65+m] = p; sum += p; }
      const float r = 1.f/sum;
      for (int m = 0; m < 64; m++) sc[t*65+m] *= r;
    }
    __syncthreads();

    // ---- PV: o_h[n][d] for d in g*6..g*6+5, write into qs (q no longer needed) ----
    {
      float acc[6];
      #pragma unroll
      for (int i = 0; i < 6; i++) acc[i] = 0.f;
      for (int m = 0; m < 64; m++) {
        const float pv = sc[n*65+m];
        #pragma unroll
        for (int di = 0; di < 6; di++)
          acc[di] += pv * vs[m*25 + g*6+di];
      }
      #pragma unroll
      for (int di = 0; di < 6; di++) qs[n*25 + g*6+di] = acc[di];
    }
    __syncthreads();

    // ---- partial proj: pacc[c] += o_h[n][:] . proj_w[c][h*24:h*24+24] ----
    for (int d = 0; d < 24; d++) {
      const float ov = qs[n*25+d];
      #pragma unroll
      for (int ci = 0; ci < 24; ci++)
        pacc[ci] += ov * proj_w[(g*24+ci)*96 + h*24 + d];   // uniform -> s_load
    }
    __syncthreads();
  }

  // ---- epilogue: out = x + proj + proj_b (re-read raw x for the residual) ----
  {
    const int ty = n >> 3, tx = n & 7;
    const size_t pix = (size_t)(y0+ty)*256 + x0 + tx;
    #pragma unroll
    for (int ci = 0; ci < 24; ci++) {
      const int c = g*24 + ci;
      const size_t idx = (size_t)(b*CC+c)*65536 + pix;
      out[idx] = x[idx] + pacc[ci] + proj_b[c];
    }
  }
}

// ---------------- Kernel 2: RMSNorm + conv1x1 + GLU, y in bf16 ----------------
// thread per pixel, 96 channels in VGPRs, weights via wave-uniform s_load.
__global__ __launch_bounds__(256) void mlp1_kernel(
    const float* __restrict__ x1,
    const float* __restrict__ mlp_norm_w,
    const float* __restrict__ w1_w,
    const float* __restrict__ w1_b,
    __hip_bfloat16* __restrict__ y)
{
  const int p  = blockIdx.x*256 + threadIdx.x;   // 0..262143
  const int b  = p >> 16;
  const int hw = p & 65535;
  const float* xp = x1 + (size_t)b*CC*65536 + hw;
  float xr[96];
  float ss = 0.f;
  #pragma unroll
  for (int c = 0; c < 96; c++) { xr[c] = xp[(size_t)c*65536]; ss += xr[c]*xr[c]; }
  const float s = rsqrtf(ss*(1.f/96.f) + 1e-6f);
  #pragma unroll
  for (int c = 0; c < 96; c++) xr[c] *= s * mlp_norm_w[c];

  __hip_bfloat16* yp = y + (size_t)b*CC*65536 + hw;
  for (int oc = 0; oc < 96; oc++) {
    float a = w1_b[oc], gg = w1_b[96+oc];
    #pragma unroll
    for (int c = 0; c < 96; c++) {
      a  += xr[c] * w1_w[oc*96+c];
      gg += xr[c] * w1_w[(96+oc)*96+c];
    }
    const float val = a / (1.f + __expf(-gg));   // a * sigmoid(g)
    yp[(size_t)oc*65536] = __float2bfloat16(val);
  }
}

// ---------------- prep: transpose conv3x3 weights to [c*9+k][oc] ----------------
__global__ void w2t_kernel(const float* __restrict__ w2, float* __restrict__ w2T)
{
  const int i = blockIdx.x*256 + threadIdx.x;
  if (i >= 96*96*9) return;
  const int oc = i / 864;
  const int rk = i - oc*864;          // c*9 + ky*3 + kx
  w2T[rk*96 + oc] = w2[i];
}

// ---------------- Kernel 3: conv3x3 (edge-pad) + leaky + residual ----------------
// block = 64-px row chunk x all 96 oc. LDS row halo 76KB -> 2 blocks/CU.
__global__ __launch_bounds__(256) void conv3_kernel(
    const __hip_bfloat16* __restrict__ y,
    const float* __restrict__ w2T,
    const float* __restrict__ w2_b,
    float* __restrict__ xout)    // holds x1 on entry; final output on exit
{
  extern __shared__ float ylds[];    // [96][3][66] = c*198 + ky*66 + px
  const int bid = blockIdx.x;
  const int b   = bid >> 10;
  const int row = (bid >> 2) & 255;
  const int px0 = (bid & 3) << 6;
  const int t   = threadIdx.x;

  for (int e = t; e < 96*3*66; e += 256) {
    const int c  = e / 198;
    const int r2 = e - c*198;
    const int ky = r2 / 66;
    const int px = r2 - ky*66;
    const int gy = min(255, max(0, row + ky - 1));
    const int gx = min(255, max(0, px0 + px - 1));
    ylds[e] = __bfloat162float(y[(size_t)(b*CC+c)*65536 + gy*256 + gx]);
  }
  __syncthreads();

  const int px = t & 63, og = t >> 6;   // wave -> 24-oc slice
  float acc[24];
  #pragma unroll
  for (int i = 0; i < 24; i++) acc[i] = 0.f;
  for (int c = 0; c < 96; c++) {
    #pragma unroll
    for (int ky = 0; ky < 3; ky++) {
      #pragma unroll
      for (int kx = 0; kx < 3; kx++) {
        const float xv = ylds[c*198 + ky*66 + px + kx];
        const float* wp = w2T + (c*9 + ky*3 + kx)*96 + og*24;  // contiguous, uniform -> s_load
        #pragma unroll
        for (int j = 0; j < 24; j++) acc[j] += xv * wp[j];
      }
    }
  }
  const size_t base = (size_t)(b*CC + og*24)*65536 + (size_t)row*256 + px0 + px;
  #pragma unroll
  for (int j = 0; j < 24; j++) {
    float v = acc[j] + w2_b[og*24+j];
    v = (v >= 0.f) ? v : 0.1f*v;
    const size_t idx = base + (size_t)j*65536;
    xout[idx] = xout[idx] + v;   // + x1 residual, in place
  }
}

extern "C" void kernel_launch(void* const* d_in, const int* in_sizes, int n_in,
                              void* d_out, int out_size, void* d_ws, size_t ws_size,
                              hipStream_t stream)
{
  (void)in_sizes; (void)n_in; (void)out_size; (void)ws_size;
  const float* x      = (const float*)d_in[0];
  const float* norm_w = (const float*)d_in[1];
  const float* qkv_w  = (const float*)d_in[2];
  const float* qkv_b  = (const float*)d_in[3];
  const float* proj_w = (const float*)d_in[4];
  const float* proj_b = (const float*)d_in[5];
  const float* btab   = (const float*)d_in[6];
  const float* mlpnw  = (const float*)d_in[7];
  const float* w1w    = (const float*)d_in[8];
  const float* w1b    = (const float*)d_in[9];
  const float* w2w    = (const float*)d_in[10];
  const float* w2b    = (const float*)d_in[11];
  float* out = (float*)d_out;

  __hip_bfloat16* y = (__hip_bfloat16*)d_ws;                       // 4*96*256*256 bf16 = 50.3MB
  float* w2T = (float*)((char*)d_ws + (size_t)25165824*2);         // +331KB

  const int ldsA = (64*97 + 3*64*25 + 64*65 + 64 + 232) * 4;       // ~61.9KB
  attn_kernel<<<4096, 256, ldsA, stream>>>(x, norm_w, qkv_w, qkv_b, proj_w, proj_b, btab, out);
  w2t_kernel<<<(96*96*9 + 255)/256, 256, 0, stream>>>(w2w, w2T);
  mlp1_kernel<<<1024, 256, 0, stream>>>(out, mlpnw, w1w, w1b, y);
  conv3_kernel<<<4096, 256, 96*3*66*4, stream>>>(y, w2T, w2b, out);
}

// Round 2
// 2654.254 us; speedup vs baseline: 1.7884x; 1.7884x over previous
//
#include <hip/hip_runtime.h>
#include <hip/hip_bf16.h>

#define CC 96

typedef short short8 __attribute__((ext_vector_type(8)));
typedef float f32x4  __attribute__((ext_vector_type(4)));

// ---------------- prep: weight transposes / packs ----------------
// qkvT [c][288]   : qkvT[c*288 + r] = qkv_w[r*96 + c]                (27648)
// projT[d][96]    : projT[d*96 + oc] = proj_w[oc*96 + d]             (9216)
// w2p  packed bf16 MFMA B-fragments                                  (82944)
// w1T  [c][192]   : w1T[c*192 + oc] = w1_w[oc*96 + c]                (18432)
__global__ void prep_kernel(const float* __restrict__ qkv_w,
                            const float* __restrict__ proj_w,
                            const float* __restrict__ w2w,
                            const float* __restrict__ w1w,
                            float* __restrict__ qkvT,
                            float* __restrict__ projT,
                            __hip_bfloat16* __restrict__ w2p,
                            float* __restrict__ w1T)
{
  const int i = blockIdx.x*256 + threadIdx.x;
  if (i < 27648) {
    const int c = i / 288, r = i - c*288;
    qkvT[i] = qkv_w[r*96 + c];
  }
  const int j = i - 27648;
  if (j >= 0 && j < 9216) {
    const int d = j / 96, oc = j - d*96;
    projT[j] = proj_w[oc*96 + d];
  }
  const int k = i - 36864;
  if (k >= 0 && k < 82944) {
    // k = ((tap*3+kc)*6+nf)*512 + lane*8 + e
    const int e = k & 7;
    const int lane = (k >> 3) & 63;
    const int rest = k >> 9;            // (tap*3+kc)*6+nf
    const int nf = rest % 6;
    const int r2 = rest / 6;
    const int kc = r2 % 3;
    const int tap = r2 / 3;
    const int cidx = kc*32 + (lane >> 4)*8 + e;
    const int oc = nf*16 + (lane & 15);
    const int ky = tap / 3, kx = tap - ky*3;
    w2p[k] = __float2bfloat16(w2w[((oc*96 + cidx)*3 + ky)*3 + kx]);
  }
  const int m = i - 119808;
  if (m >= 0 && m < 18432) {
    const int c = m / 192, oc = m - c*192;
    w1T[m] = w1w[oc*96 + c];
  }
}

// ---------------- Kernel 1: windowed MHA (RMSNorm fused) + residual ----------------
__global__ __launch_bounds__(256) void attn_kernel(
    const float* __restrict__ x,
    const float* __restrict__ norm_w,
    const float* __restrict__ qkvT,     // [96][288]
    const float* __restrict__ qkv_b,
    const float* __restrict__ projT,    // [96][96] transposed
    const float* __restrict__ proj_b,
    const float* __restrict__ bias_table,
    float* __restrict__ out)
{
  extern __shared__ float lds[];
  float* xr   = lds;             // [64][97]
  float* qs   = xr + 64*97;      // [64][25]
  float* ks   = qs + 64*25;      // [64][25]
  float* vs   = ks + 64*25;      // [64][25]
  float* sc   = vs + 64*25;      // [64][65]
  float* scl  = sc + 64*65;      // [64]
  float* btab = scl + 64;        // [225]

  const int wid = blockIdx.x;
  const int b  = wid >> 10;
  const int wy = (wid >> 5) & 31;
  const int wx = wid & 31;
  const int t  = threadIdx.x;
  const int y0 = wy*8, x0 = wx*8;

  for (int i = t; i < 225; i += 256) btab[i] = bias_table[i];

  for (int e = t; e < 1536; e += 256) {
    const int c   = e >> 4;
    const int q4  = e & 15;
    const int ty  = q4 >> 1;
    const int tx0 = (q4 & 1) << 2;
    const float4 v = *(const float4*)(x + (size_t)(b*CC+c)*65536 + (size_t)(y0+ty)*256 + x0 + tx0);
    const int n = ty*8 + tx0;
    xr[(n+0)*97 + c] = v.x;
    xr[(n+1)*97 + c] = v.y;
    xr[(n+2)*97 + c] = v.z;
    xr[(n+3)*97 + c] = v.w;
  }
  __syncthreads();

  if (t < 64) {
    float ss = 0.f;
    #pragma unroll
    for (int c = 0; c < 96; c++) { const float u = xr[t*97+c]; ss += u*u; }
    scl[t] = rsqrtf(ss * (1.0f/96.0f) + 1e-6f);
  }
  __syncthreads();
  for (int e = t; e < 6144; e += 256) {
    const int nn = e / 96, c = e - nn*96;
    xr[nn*97+c] *= scl[nn] * norm_w[c];
  }
  __syncthreads();

  const int n = t & 63;
  const int g = __builtin_amdgcn_readfirstlane(t >> 6);   // provably wave-uniform
  float pacc[24];
  #pragma unroll
  for (int i = 0; i < 24; i++) pacc[i] = 0.f;

  for (int h = 0; h < 4; h++) {
    int off[18];
    #pragma unroll
    for (int i = 0; i < 18; i++) {
      const int j = g*18 + i;
      const int sI = j / 24, dd = j - sI*24;
      off[i] = sI*96 + h*24 + dd;
    }
    // ---- QKV: uniform s_loads from transposed weights ----
    {
      float acc[18];
      #pragma unroll
      for (int i = 0; i < 18; i++) acc[i] = 0.f;
      for (int c = 0; c < 96; c++) {
        const float xv = xr[n*97+c];
        const float* qb = qkvT + c*288;
        #pragma unroll
        for (int i = 0; i < 18; i++) acc[i] += xv * qb[off[i]];
      }
      #pragma unroll
      for (int i = 0; i < 18; i++) {
        const int j = g*18 + i;
        const int sI = j / 24, dd = j - sI*24;
        const float val = acc[i] + qkv_b[off[i]];
        if (sI == 0)      qs[n*25+dd] = val;
        else if (sI == 1) ks[n*25+dd] = val;
        else              vs[n*25+dd] = val;
      }
    }
    __syncthreads();

    // ---- scores ----
    {
      float acc[16];
      #pragma unroll
      for (int i = 0; i < 16; i++) acc[i] = 0.f;
      for (int d = 0; d < 24; d++) {
        const float qv = qs[n*25+d];
        #pragma unroll
        for (int mi = 0; mi < 16; mi++)
          acc[mi] += qv * ks[(g*16+mi)*25 + d];
      }
      const int ny = n >> 3, nx = n & 7;
      #pragma unroll
      for (int mi = 0; mi < 16; mi++) {
        const int m = g*16 + mi;
        const int my = m >> 3, mx = m & 7;
        sc[n*65+m] = acc[mi] * 0.20412414523193154f
                   + btab[(ny-my+7)*15 + (nx-mx+7)];
      }
    }
    __syncthreads();

    // ---- softmax: 4 lanes per row, shfl reduce ----
    {
      const int r = t >> 2, q = t & 3;
      float mx = -1e30f;
      #pragma unroll
      for (int mi = 0; mi < 16; mi++) mx = fmaxf(mx, sc[r*65 + q*16 + mi]);
      mx = fmaxf(mx, __shfl_xor(mx, 1));
      mx = fmaxf(mx, __shfl_xor(mx, 2));
      float p[16];
      float sum = 0.f;
      #pragma unroll
      for (int mi = 0; mi < 16; mi++) { p[mi] = __expf(sc[r*65+q*16+mi] - mx); sum += p[mi]; }
      sum += __shfl_xor(sum, 1);
      sum += __shfl_xor(sum, 2);
      const float rs = 1.f / sum;
      #pragma unroll
      for (int mi = 0; mi < 16; mi++) sc[r*65+q*16+mi] = p[mi]*rs;
    }
    __syncthreads();

    // ---- PV ----
    {
      float acc[6];
      #pragma unroll
      for (int i = 0; i < 6; i++) acc[i] = 0.f;
      for (int m = 0; m < 64; m++) {
        const float pv = sc[n*65+m];
        #pragma unroll
        for (int di = 0; di < 6; di++)
          acc[di] += pv * vs[m*25 + g*6+di];
      }
      #pragma unroll
      for (int di = 0; di < 6; di++) qs[n*25 + g*6+di] = acc[di];
    }
    __syncthreads();

    // ---- partial proj: contiguous uniform s_loads ----
    for (int d = 0; d < 24; d++) {
      const float ov = qs[n*25+d];
      const float* pb = projT + (h*24+d)*96 + g*24;
      #pragma unroll
      for (int ci = 0; ci < 24; ci++)
        pacc[ci] += ov * pb[ci];
    }
    __syncthreads();
  }

  {
    const int ty = n >> 3, tx = n & 7;
    const size_t pix = (size_t)(y0+ty)*256 + x0 + tx;
    #pragma unroll
    for (int ci = 0; ci < 24; ci++) {
      const int c = g*24 + ci;
      const size_t idx = (size_t)(b*CC+c)*65536 + pix;
      out[idx] = x[idx] + pacc[ci] + proj_b[c];
    }
  }
}

// ---------------- Kernel 2: RMSNorm + conv1x1 + GLU -> y bf16 [b][hw][96] ----------------
__global__ __launch_bounds__(256) void mlp1_kernel(
    const float* __restrict__ x1,
    const float* __restrict__ mlp_norm_w,
    const float* __restrict__ w1T,      // [96][192]
    const float* __restrict__ w1_b,
    __hip_bfloat16* __restrict__ y)     // [b][hw][96]
{
  const int p  = blockIdx.x*256 + threadIdx.x;
  const int b  = p >> 16;
  const int hw = p & 65535;
  const float* xp = x1 + (size_t)b*CC*65536 + hw;
  float xr[96];
  float ss = 0.f;
  #pragma unroll
  for (int c = 0; c < 96; c++) { xr[c] = xp[(size_t)c*65536]; ss += xr[c]*xr[c]; }
  const float s = rsqrtf(ss*(1.f/96.f) + 1e-6f);
  #pragma unroll
  for (int c = 0; c < 96; c++) xr[c] *= s * mlp_norm_w[c];

  __hip_bfloat16* yp = y + (size_t)p * 96;
  for (int ocg = 0; ocg < 12; ++ocg) {
    float a[8], gg[8];
    #pragma unroll
    for (int j2 = 0; j2 < 8; ++j2) { a[j2] = w1_b[ocg*8+j2]; gg[j2] = w1_b[96+ocg*8+j2]; }
    #pragma unroll
    for (int c = 0; c < 96; ++c) {
      const float xv = xr[c];
      const float* wb = w1T + c*192 + ocg*8;
      #pragma unroll
      for (int j2 = 0; j2 < 8; ++j2) {
        a[j2]  += xv * wb[j2];
        gg[j2] += xv * wb[96+j2];
      }
    }
    union { ushort u[8]; uint4 v4; } pk;
    #pragma unroll
    for (int j2 = 0; j2 < 8; ++j2) {
      const float val = a[j2] / (1.f + __expf(-gg[j2]));
      __hip_bfloat16 bh = __float2bfloat16(val);
      pk.u[j2] = *reinterpret_cast<const ushort*>(&bh);
    }
    *reinterpret_cast<uint4*>(yp + ocg*8) = pk.v4;
  }
}

// ---------------- Kernel 3: conv3x3 via MFMA implicit GEMM + leaky + residual ----------------
// tile: 128 px (2 rows x 64) x 96 oc, K = 96c x 9 taps. 4 waves.
__global__ __launch_bounds__(256) void conv3_kernel(
    const __hip_bfloat16* __restrict__ y,    // [b][hw][96]
    const __hip_bfloat16* __restrict__ w2p,  // packed fragments
    const float* __restrict__ w2_b,
    float* __restrict__ xout)
{
  extern __shared__ char smem[];
  ushort* A = (ushort*)smem;         // [4 rows][66 px][104 c-pad] bf16
  float*  O = (float*)smem;          // [96 oc][132 m-pad] f32 (reused after barrier)

  const int bid = blockIdx.x;        // b*512 + rp*4 + ch
  const int b   = bid >> 9;
  const int rp  = (bid >> 2) & 127;
  const int ch  = bid & 3;
  const int px0 = ch << 6;
  const int t   = threadIdx.x;
  const int w   = __builtin_amdgcn_readfirstlane(t >> 6);
  const int l   = t & 63;
  const int m15 = l & 15, lh = l >> 4;

  // ---- stage 4 input rows (clamped) into LDS, channel-contiguous ----
  for (int e = t; e < 3168; e += 256) {
    const int seg  = e / 12;          // ky*66+px, 0..263
    const int part = e - seg*12;      // 16B chunk
    const int ky = seg / 66;
    const int px = seg - ky*66;
    const int gy = min(255, max(0, 2*rp + ky - 1));
    const int gx = min(255, max(0, px0 + px - 1));
    const short8 v = *(const short8*)(y + ((size_t)(b*65536 + gy*256 + gx))*96 + part*8);
    *(short8*)(A + seg*104 + part*8) = v;
  }
  __syncthreads();

  f32x4 acc0[6], acc1[6];
  #pragma unroll
  for (int nf = 0; nf < 6; ++nf) { acc0[nf] = (f32x4)0.f; acc1[nf] = (f32x4)0.f; }

  for (int tap = 0; tap < 9; ++tap) {
    const int ky = tap / 3, kx = tap - ky*3;
    for (int kc = 0; kc < 3; ++kc) {
      const int cb = kc*32 + lh*8;
      const short8 a0 = *(const short8*)(A + ((ky  )*66 + 16*w + m15 + kx)*104 + cb);
      const short8 a1 = *(const short8*)(A + ((ky+1)*66 + 16*w + m15 + kx)*104 + cb);
      const short8* bp = (const short8*)w2p + ((size_t)(tap*3 + kc)*6)*64 + l;
      #pragma unroll
      for (int nf = 0; nf < 6; ++nf) {
        const short8 bf = bp[nf*64];
        acc0[nf] = __builtin_amdgcn_mfma_f32_16x16x32_bf16(a0, bf, acc0[nf], 0, 0, 0);
        acc1[nf] = __builtin_amdgcn_mfma_f32_16x16x32_bf16(a1, bf, acc1[nf], 0, 0, 0);
      }
    }
  }
  __syncthreads();

  // ---- write accumulators to LDS [oc][m] for coalesced store ----
  {
    const int jb = 16*w + lh*4;
    #pragma unroll
    for (int nf = 0; nf < 6; ++nf) {
      const int oc = nf*16 + m15;
      *(f32x4*)(O + oc*132 + jb)      = acc0[nf];
      *(f32x4*)(O + oc*132 + 64 + jb) = acc1[nf];
    }
  }
  __syncthreads();

  // ---- epilogue: bias + leaky + residual, coalesced f32x4 ----
  for (int e = t; e < 3072; e += 256) {
    const int oc = e >> 5;
    const int j  = (e & 31) * 4;      // 0..124
    f32x4 v = *(const f32x4*)(O + oc*132 + j);
    const float bb = w2_b[oc];
    const int gy = 2*rp + (j >> 6);
    const int px = px0 + (j & 63);
    float* op = xout + ((size_t)(b*CC + oc))*65536 + (size_t)gy*256 + px;
    f32x4 r = *(const f32x4*)op;
    #pragma unroll
    for (int q = 0; q < 4; ++q) {
      float u = v[q] + bb;
      u = (u >= 0.f) ? u : 0.1f*u;
      r[q] += u;
    }
    *(f32x4*)op = r;
  }
}

extern "C" void kernel_launch(void* const* d_in, const int* in_sizes, int n_in,
                              void* d_out, int out_size, void* d_ws, size_t ws_size,
                              hipStream_t stream)
{
  (void)in_sizes; (void)n_in; (void)out_size; (void)ws_size;
  const float* x      = (const float*)d_in[0];
  const float* norm_w = (const float*)d_in[1];
  const float* qkv_w  = (const float*)d_in[2];
  const float* qkv_b  = (const float*)d_in[3];
  const float* proj_w = (const float*)d_in[4];
  const float* proj_b = (const float*)d_in[5];
  const float* btab   = (const float*)d_in[6];
  const float* mlpnw  = (const float*)d_in[7];
  const float* w1w    = (const float*)d_in[8];
  const float* w1b    = (const float*)d_in[9];
  const float* w2w    = (const float*)d_in[10];
  const float* w2b    = (const float*)d_in[11];
  float* out = (float*)d_out;

  char* ws = (char*)d_ws;
  __hip_bfloat16* y    = (__hip_bfloat16*)ws;                         // 50,331,648 B
  __hip_bfloat16* w2p  = (__hip_bfloat16*)(ws + 50331648);            // 165,888 B
  float*          qkvT = (float*)(ws + 50497536);                     // 110,592 B
  float*          projT= (float*)(ws + 50608128);                     // 36,864 B
  float*          w1T  = (float*)(ws + 50644992);                     // 73,728 B

  prep_kernel<<<540, 256, 0, stream>>>(qkv_w, proj_w, w2w, w1w, qkvT, projT, w2p, w1T);

  const int ldsA = (64*97 + 3*64*25 + 64*65 + 64 + 232) * 4;
  attn_kernel<<<4096, 256, ldsA, stream>>>(x, norm_w, qkvT, qkv_b, projT, proj_b, btab, out);
  mlp1_kernel<<<1024, 256, 0, stream>>>(out, mlpnw, w1T, w1b, y);
  conv3_kernel<<<2048, 256, 54912, stream>>>(y, w2p, w2b, out);
}

// Round 3
// 1284.163 us; speedup vs baseline: 3.6964x; 2.0669x over previous
//
#include <hip/hip_runtime.h>
#include <hip/hip_bf16.h>

#define CC 96

typedef short short8  __attribute__((ext_vector_type(8)));
typedef short short4v __attribute__((ext_vector_type(4)));
typedef float f32x4   __attribute__((ext_vector_type(4)));

static __device__ __forceinline__ ushort f2bf(float f) {
  __hip_bfloat16 h = __float2bfloat16(f);
  return *reinterpret_cast<ushort*>(&h);
}
static __device__ __forceinline__ float bf2f(ushort u) {
  union { unsigned int u; float f; } v; v.u = ((unsigned int)u) << 16; return v.f;
}

// ---------------- prep: pack all weights ----------------
// qkvp [h][ks][nt][lane][8] bf16 (36864): B-frags for QKV GEMM, per-head N=96 (q32|k32|v32, d>=24 zero)
// projp [ks][nt][lane][8] bf16 (9216):  B-frags for proj GEMM
// w2p   conv3 B-frags bf16 (82944)
// w1T   [c][192] f32 (18432)
__global__ void prep_kernel(const float* __restrict__ qkv_w,
                            const float* __restrict__ proj_w,
                            const float* __restrict__ w2w,
                            const float* __restrict__ w1w,
                            __hip_bfloat16* __restrict__ qkvp,
                            __hip_bfloat16* __restrict__ projp,
                            __hip_bfloat16* __restrict__ w2p,
                            float* __restrict__ w1T)
{
  const int i = blockIdx.x*256 + threadIdx.x;
  if (i < 36864) {
    const int e = i & 7, lane = (i >> 3) & 63;
    const int rest = i >> 9;           // (h*3+ks)*6+nt
    const int nt = rest % 6, r2 = rest / 6;
    const int ks = r2 % 3, h = r2 / 3;
    const int col = nt*16 + (lane & 15);
    const int sec = col >> 5, d = col & 31;
    const int c = ks*32 + (lane >> 4)*8 + e;
    const float val = (d < 24) ? qkv_w[(sec*96 + h*24 + d)*96 + c] : 0.f;
    qkvp[i] = __float2bfloat16(val);
  }
  const int j = i - 36864;
  if (j >= 0 && j < 9216) {
    const int e = j & 7, lane = (j >> 3) & 63;
    const int rest = j >> 9;           // ks*6+nt
    const int nt = rest % 6, ks = rest / 6;
    const int oc = nt*16 + (lane & 15);
    const int dd = ks*32 + (lane >> 4)*8 + e;
    projp[j] = __float2bfloat16(proj_w[oc*96 + dd]);
  }
  const int k = i - 46080;
  if (k >= 0 && k < 82944) {
    const int e = k & 7;
    const int lane = (k >> 3) & 63;
    const int rest = k >> 9;           // (tap*3+kc)*6+nf
    const int nf = rest % 6;
    const int r2 = rest / 6;
    const int kc = r2 % 3;
    const int tap = r2 / 3;
    const int cidx = kc*32 + (lane >> 4)*8 + e;
    const int oc = nf*16 + (lane & 15);
    const int ky = tap / 3, kx = tap - ky*3;
    w2p[k] = __float2bfloat16(w2w[((oc*96 + cidx)*3 + ky)*3 + kx]);
  }
  const int m = i - 129024;
  if (m >= 0 && m < 18432) {
    const int c = m / 192, oc = m - c*192;
    w1T[m] = w1w[oc*96 + c];
  }
}

// ---------------- Kernel 1: windowed MHA via MFMA + residual ----------------
// block = 256 (4 waves), 1 window; wave h owns head h. LDS 65412B -> 2 blocks/CU.
__global__ __launch_bounds__(256, 2) void attn_kernel(
    const float* __restrict__ x,
    const float* __restrict__ norm_w,
    const __hip_bfloat16* __restrict__ qkvp,
    const float* __restrict__ qkv_b,
    const __hip_bfloat16* __restrict__ projp,
    const float* __restrict__ proj_b,
    const float* __restrict__ bias_table,
    float* __restrict__ out)
{
  extern __shared__ char smem[];
  ushort* xn   = (ushort*)smem;              // [64][104] bf16: xn, later o, later outT[96][68]
  float*  xf   = (float*)(smem + 13312);     // [64][97] f32 (phase 1 only, overlays head regions)
  float*  btab = (float*)(smem + 64512);     // [225]

  const int wid = blockIdx.x;
  const int b  = wid >> 10;
  const int wy = (wid >> 5) & 31;
  const int wx = wid & 31;
  const int t  = threadIdx.x;
  const int y0 = wy*8, x0 = wx*8;
  const int l  = t & 63;
  const int w  = __builtin_amdgcn_readfirstlane(t >> 6);
  const int lr = l & 15, g = l >> 4;

  for (int i = t; i < 225; i += 256) btab[i] = bias_table[i];

  // ---- P1: window -> xf f32 ----
  for (int e = t; e < 1536; e += 256) {
    const int c = e >> 4, q4 = e & 15;
    const int ty = q4 >> 1, tx0 = (q4 & 1) << 2;
    const float4 v = *(const float4*)(x + (size_t)(b*CC+c)*65536 + (size_t)(y0+ty)*256 + x0 + tx0);
    const int n = ty*8 + tx0;
    xf[(n+0)*97+c] = v.x; xf[(n+1)*97+c] = v.y; xf[(n+2)*97+c] = v.z; xf[(n+3)*97+c] = v.w;
  }
  __syncthreads();

  // ---- P1.5: RMSNorm -> xn bf16 ----
  {
    const int n = t >> 2, c0 = (t & 3) * 24;
    float ss = 0.f;
    #pragma unroll
    for (int i = 0; i < 24; i++) { const float u = xf[n*97 + c0 + i]; ss += u*u; }
    ss += __shfl_xor(ss, 1);
    ss += __shfl_xor(ss, 2);
    const float s = rsqrtf(ss * (1.f/96.f) + 1e-6f);
    #pragma unroll
    for (int i = 0; i < 24; i++) {
      const int c = c0 + i;
      xn[n*104 + c] = f2bf(xf[n*97+c] * s * norm_w[c]);
    }
  }
  __syncthreads();

  const int h = w;
  char* hbase = smem + 13312 + h*12800;
  ushort* Qs = (ushort*)hbase;               // [64][32] bf16
  ushort* Ks = (ushort*)(hbase + 4096);      // [64][32]
  ushort* Vt = (ushort*)(hbase + 8192);      // [32][72]
  ushort* Ps = (ushort*)hbase;               // [64][64] swizzled, overlays Q+K

  // ---- P2: QKV GEMM (A=xn, B=qkvp frags) ----
  f32x4 acc[4][6];
  #pragma unroll
  for (int mt = 0; mt < 4; mt++)
    #pragma unroll
    for (int nt = 0; nt < 6; nt++) acc[mt][nt] = (f32x4)0.f;

  #pragma unroll
  for (int ks = 0; ks < 3; ks++) {
    short8 afr[4];
    #pragma unroll
    for (int mt = 0; mt < 4; mt++)
      afr[mt] = *(const short8*)((const char*)xn + (lr + mt*16)*208 + g*16 + ks*64);
    #pragma unroll
    for (int nt = 0; nt < 6; nt++) {
      const short8 bfr = *(const short8*)(qkvp + ((h*3+ks)*6+nt)*512 + l*8);
      #pragma unroll
      for (int mt = 0; mt < 4; mt++)
        acc[mt][nt] = __builtin_amdgcn_mfma_f32_16x16x32_bf16(afr[mt], bfr, acc[mt][nt], 0, 0, 0);
    }
  }
  __syncthreads();   // all xn reads done (xn region becomes o later)

  // ---- write Q,K (b16) and Vt (b64, transposed) ----
  #pragma unroll
  for (int nt = 0; nt < 4; nt++) {
    const int sec  = nt >> 1;              // 0=Q, 1=K
    const int dcol = lr + (nt & 1)*16;
    ushort* dst = sec ? Ks : Qs;
    const float bias = (dcol < 24) ? qkv_b[sec*96 + h*24 + dcol] : 0.f;
    #pragma unroll
    for (int mt = 0; mt < 4; mt++)
      #pragma unroll
      for (int r = 0; r < 4; r++) {
        const int row = g*4 + r + mt*16;
        const float val = (dcol < 24) ? (acc[mt][nt][r] + bias) : 0.f;
        dst[row*32 + dcol] = f2bf(val);
      }
  }
  #pragma unroll
  for (int nt = 4; nt < 6; nt++) {
    const int vd = lr + (nt-4)*16;
    const float bias = (vd < 24) ? qkv_b[192 + h*24 + vd] : 0.f;
    #pragma unroll
    for (int mt = 0; mt < 4; mt++) {
      short4v pk;
      #pragma unroll
      for (int r = 0; r < 4; r++) {
        const float val = (vd < 24) ? (acc[mt][nt][r] + bias) : 0.f;
        pk[r] = (short)f2bf(val);
      }
      *(short4v*)((char*)Vt + vd*144 + (g*4 + mt*16)*2) = pk;
    }
  }

  // ---- P3: scores = mfma(Q, K) ----
  f32x4 sacc[4][4];
  {
    short8 qf[4], kf[4];
    #pragma unroll
    for (int mt = 0; mt < 4; mt++) qf[mt] = *(const short8*)((char*)Qs + (lr+mt*16)*64 + g*16);
    #pragma unroll
    for (int nt = 0; nt < 4; nt++) kf[nt] = *(const short8*)((char*)Ks + (lr+nt*16)*64 + g*16);
    #pragma unroll
    for (int mt = 0; mt < 4; mt++)
      #pragma unroll
      for (int nt = 0; nt < 4; nt++)
        sacc[mt][nt] = __builtin_amdgcn_mfma_f32_16x16x32_bf16(qf[mt], kf[nt], (f32x4)0.f, 0, 0, 0);
  }

  // ---- softmax (+scale+bias), write P swizzled bf16 ----
  {
    const float SCALE = 0.20412414523193154f;
    int bk[4];
    #pragma unroll
    for (int nt = 0; nt < 4; nt++) {
      const int k = lr + nt*16;
      bk[nt] = 112 - ((k >> 3)*15 + (k & 7));
    }
    #pragma unroll
    for (int mt = 0; mt < 4; mt++)
      #pragma unroll
      for (int r = 0; r < 4; r++) {
        const int q  = g*4 + r + mt*16;
        const int aq = (q >> 3)*15 + (q & 7);
        float v[4];
        #pragma unroll
        for (int nt = 0; nt < 4; nt++) v[nt] = sacc[mt][nt][r]*SCALE + btab[aq + bk[nt]];
        float mx = fmaxf(fmaxf(v[0], v[1]), fmaxf(v[2], v[3]));
        mx = fmaxf(mx, __shfl_xor(mx, 1));
        mx = fmaxf(mx, __shfl_xor(mx, 2));
        mx = fmaxf(mx, __shfl_xor(mx, 4));
        mx = fmaxf(mx, __shfl_xor(mx, 8));
        float e[4], s = 0.f;
        #pragma unroll
        for (int nt = 0; nt < 4; nt++) { e[nt] = __expf(v[nt]-mx); s += e[nt]; }
        s += __shfl_xor(s, 1); s += __shfl_xor(s, 2);
        s += __shfl_xor(s, 4); s += __shfl_xor(s, 8);
        const float rinv = 1.0f / s;
        const int sw = (q & 7) << 4;
        #pragma unroll
        for (int nt = 0; nt < 4; nt++) {
          const int kk = (lr + nt*16)*2;
          *(ushort*)((char*)Ps + q*128 + (kk ^ sw)) = f2bf(e[nt]*rinv);
        }
      }
  }

  // ---- P4: o = mfma(P, Vt), write into xn region ----
  {
    f32x4 oacc[4][2];
    #pragma unroll
    for (int mt = 0; mt < 4; mt++) { oacc[mt][0] = (f32x4)0.f; oacc[mt][1] = (f32x4)0.f; }
    #pragma unroll
    for (int ks = 0; ks < 2; ks++) {
      short8 pf[4], vf[2];
      #pragma unroll
      for (int mt = 0; mt < 4; mt++) {
        const int row = lr + mt*16;
        pf[mt] = *(const short8*)((char*)Ps + row*128 + ((g*16 + ks*64) ^ ((row & 7) << 4)));
      }
      #pragma unroll
      for (int nt = 0; nt < 2; nt++)
        vf[nt] = *(const short8*)((char*)Vt + (lr+nt*16)*144 + g*16 + ks*64);
      #pragma unroll
      for (int mt = 0; mt < 4; mt++)
        #pragma unroll
        for (int nt = 0; nt < 2; nt++)
          oacc[mt][nt] = __builtin_amdgcn_mfma_f32_16x16x32_bf16(pf[mt], vf[nt], oacc[mt][nt], 0, 0, 0);
    }
    ushort* oM = xn;
    #pragma unroll
    for (int nt = 0; nt < 2; nt++) {
      const int d0 = lr + nt*16;
      if (d0 < 24) {
        #pragma unroll
        for (int mt = 0; mt < 4; mt++)
          #pragma unroll
          for (int r = 0; r < 4; r++) {
            const int row = g*4 + r + mt*16;
            oM[row*104 + h*24 + d0] = f2bf(oacc[mt][nt][r]);
          }
      }
    }
  }
  __syncthreads();   // o complete

  // ---- P5: proj (wave w owns mtile w) ----
  {
    f32x4 pacc[6];
    #pragma unroll
    for (int nt = 0; nt < 6; nt++) pacc[nt] = (f32x4)0.f;
    #pragma unroll
    for (int ks = 0; ks < 3; ks++) {
      const short8 af = *(const short8*)((const char*)xn + (lr + w*16)*208 + g*16 + ks*64);
      #pragma unroll
      for (int nt = 0; nt < 6; nt++) {
        const short8 bf = *(const short8*)(projp + (ks*6+nt)*512 + l*8);
        pacc[nt] = __builtin_amdgcn_mfma_f32_16x16x32_bf16(af, bf, pacc[nt], 0, 0, 0);
      }
    }
    __syncthreads();   // all o reads done; xn region becomes outT[96][68]
    ushort* oT = xn;
    #pragma unroll
    for (int nt = 0; nt < 6; nt++) {
      const int oc = lr + nt*16;
      const float bias = proj_b[oc];
      short4v pk;
      #pragma unroll
      for (int r = 0; r < 4; r++) pk[r] = (short)f2bf(pacc[nt][r] + bias);
      *(short4v*)((char*)oT + oc*136 + (g*4 + w*16)*2) = pk;
    }
  }
  __syncthreads();

  // ---- epilogue: out = x + attn, coalesced float4 ----
  {
    const ushort* oT = xn;
    #pragma unroll
    for (int k2 = 0; k2 < 6; k2++) {
      const int v = t + k2*256;
      const int oc = v >> 4, pq = v & 15;
      const int ty = pq >> 1, tx4 = (pq & 1) << 2;
      const int pl = ty*8 + tx4;
      const short4v ov = *(const short4v*)((const char*)oT + oc*136 + pl*2);
      const size_t gidx = (size_t)(b*CC+oc)*65536 + (size_t)(y0+ty)*256 + x0 + tx4;
      float4 xv = *(const float4*)(x + gidx);
      float4 res;
      res.x = xv.x + bf2f((ushort)ov[0]);
      res.y = xv.y + bf2f((ushort)ov[1]);
      res.z = xv.z + bf2f((ushort)ov[2]);
      res.w = xv.w + bf2f((ushort)ov[3]);
      *(float4*)(out + gidx) = res;
    }
  }
}

// ---------------- Kernel 2: RMSNorm + conv1x1 + GLU -> y bf16 [b][hw][96] ----------------
__global__ __launch_bounds__(256) void mlp1_kernel(
    const float* __restrict__ x1,
    const float* __restrict__ mlp_norm_w,
    const float* __restrict__ w1T,      // [96][192]
    const float* __restrict__ w1_b,
    __hip_bfloat16* __restrict__ y)     // [b][hw][96]
{
  const int p  = blockIdx.x*256 + threadIdx.x;
  const int b  = p >> 16;
  const int hw = p & 65535;
  const float* xp = x1 + (size_t)b*CC*65536 + hw;
  float xr[96];
  float ss = 0.f;
  #pragma unroll
  for (int c = 0; c < 96; c++) { xr[c] = xp[(size_t)c*65536]; ss += xr[c]*xr[c]; }
  const float s = rsqrtf(ss*(1.f/96.f) + 1e-6f);
  #pragma unroll
  for (int c = 0; c < 96; c++) xr[c] *= s * mlp_norm_w[c];

  __hip_bfloat16* yp = y + (size_t)p * 96;
  for (int ocg = 0; ocg < 12; ++ocg) {
    float a[8], gg[8];
    #pragma unroll
    for (int j2 = 0; j2 < 8; ++j2) { a[j2] = w1_b[ocg*8+j2]; gg[j2] = w1_b[96+ocg*8+j2]; }
    #pragma unroll
    for (int c = 0; c < 96; ++c) {
      const float xv = xr[c];
      const float* wb = w1T + c*192 + ocg*8;
      #pragma unroll
      for (int j2 = 0; j2 < 8; ++j2) {
        a[j2]  += xv * wb[j2];
        gg[j2] += xv * wb[96+j2];
      }
    }
    union { ushort u[8]; uint4 v4; } pk;
    #pragma unroll
    for (int j2 = 0; j2 < 8; ++j2) {
      const float val = a[j2] / (1.f + __expf(-gg[j2]));
      pk.u[j2] = f2bf(val);
    }
    *reinterpret_cast<uint4*>(yp + ocg*8) = pk.v4;
  }
}

// ---------------- Kernel 3: conv3x3 via MFMA implicit GEMM + leaky + residual ----------------
__global__ __launch_bounds__(256) void conv3_kernel(
    const __hip_bfloat16* __restrict__ y,    // [b][hw][96]
    const __hip_bfloat16* __restrict__ w2p,  // packed fragments
    const float* __restrict__ w2_b,
    float* __restrict__ xout)
{
  extern __shared__ char smem[];
  ushort* A = (ushort*)smem;         // [4 rows][66 px][104 c-pad] bf16
  float*  O = (float*)smem;          // [96 oc][132 m-pad] f32 (reused after barrier)

  const int bid = blockIdx.x;        // b*512 + rp*4 + ch
  const int b   = bid >> 9;
  const int rp  = (bid >> 2) & 127;
  const int ch  = bid & 3;
  const int px0 = ch << 6;
  const int t   = threadIdx.x;
  const int w   = __builtin_amdgcn_readfirstlane(t >> 6);
  const int l   = t & 63;
  const int m15 = l & 15, lh = l >> 4;

  for (int e = t; e < 3168; e += 256) {
    const int seg  = e / 12;
    const int part = e - seg*12;
    const int ky = seg / 66;
    const int px = seg - ky*66;
    const int gy = min(255, max(0, 2*rp + ky - 1));
    const int gx = min(255, max(0, px0 + px - 1));
    const short8 v = *(const short8*)(y + ((size_t)(b*65536 + gy*256 + gx))*96 + part*8);
    *(short8*)(A + seg*104 + part*8) = v;
  }
  __syncthreads();

  f32x4 acc0[6], acc1[6];
  #pragma unroll
  for (int nf = 0; nf < 6; ++nf) { acc0[nf] = (f32x4)0.f; acc1[nf] = (f32x4)0.f; }

  for (int tap = 0; tap < 9; ++tap) {
    const int ky = tap / 3, kx = tap - ky*3;
    for (int kc = 0; kc < 3; ++kc) {
      const int cb = kc*32 + lh*8;
      const short8 a0 = *(const short8*)(A + ((ky  )*66 + 16*w + m15 + kx)*104 + cb);
      const short8 a1 = *(const short8*)(A + ((ky+1)*66 + 16*w + m15 + kx)*104 + cb);
      const short8* bp = (const short8*)w2p + ((size_t)(tap*3 + kc)*6)*64 + l;
      #pragma unroll
      for (int nf = 0; nf < 6; ++nf) {
        const short8 bf = bp[nf*64];
        acc0[nf] = __builtin_amdgcn_mfma_f32_16x16x32_bf16(a0, bf, acc0[nf], 0, 0, 0);
        acc1[nf] = __builtin_amdgcn_mfma_f32_16x16x32_bf16(a1, bf, acc1[nf], 0, 0, 0);
      }
    }
  }
  __syncthreads();

  {
    const int jb = 16*w + lh*4;
    #pragma unroll
    for (int nf = 0; nf < 6; ++nf) {
      const int oc = nf*16 + m15;
      *(f32x4*)(O + oc*132 + jb)      = acc0[nf];
      *(f32x4*)(O + oc*132 + 64 + jb) = acc1[nf];
    }
  }
  __syncthreads();

  for (int e = t; e < 3072; e += 256) {
    const int oc = e >> 5;
    const int j  = (e & 31) * 4;
    f32x4 v = *(const f32x4*)(O + oc*132 + j);
    const float bb = w2_b[oc];
    const int gy = 2*rp + (j >> 6);
    const int px = px0 + (j & 63);
    float* op = xout + ((size_t)(b*CC + oc))*65536 + (size_t)gy*256 + px;
    f32x4 r = *(const f32x4*)op;
    #pragma unroll
    for (int q = 0; q < 4; ++q) {
      float u = v[q] + bb;
      u = (u >= 0.f) ? u : 0.1f*u;
      r[q] += u;
    }
    *(f32x4*)op = r;
  }
}

extern "C" void kernel_launch(void* const* d_in, const int* in_sizes, int n_in,
                              void* d_out, int out_size, void* d_ws, size_t ws_size,
                              hipStream_t stream)
{
  (void)in_sizes; (void)n_in; (void)out_size; (void)ws_size;
  const float* x      = (const float*)d_in[0];
  const float* norm_w = (const float*)d_in[1];
  const float* qkv_w  = (const float*)d_in[2];
  const float* qkv_b  = (const float*)d_in[3];
  const float* proj_w = (const float*)d_in[4];
  const float* proj_b = (const float*)d_in[5];
  const float* btab   = (const float*)d_in[6];
  const float* mlpnw  = (const float*)d_in[7];
  const float* w1w    = (const float*)d_in[8];
  const float* w1b    = (const float*)d_in[9];
  const float* w2w    = (const float*)d_in[10];
  const float* w2b    = (const float*)d_in[11];
  float* out = (float*)d_out;

  char* ws = (char*)d_ws;
  __hip_bfloat16* y     = (__hip_bfloat16*)ws;                    // 50,331,648 B
  __hip_bfloat16* w2p   = (__hip_bfloat16*)(ws + 50331648);       // 165,888 B
  __hip_bfloat16* qkvp  = (__hip_bfloat16*)(ws + 50497536);       // 73,728 B
  __hip_bfloat16* projp = (__hip_bfloat16*)(ws + 50571264);       // 18,432 B
  float*          w1T   = (float*)(ws + 50589696);                // 73,728 B

  prep_kernel<<<576, 256, 0, stream>>>(qkv_w, proj_w, w2w, w1w, qkvp, projp, w2p, w1T);

  attn_kernel<<<4096, 256, 65412, stream>>>(x, norm_w, qkvp, qkv_b, projp, proj_b, btab, out);
  mlp1_kernel<<<1024, 256, 0, stream>>>(out, mlpnw, w1T, w1b, y);
  conv3_kernel<<<2048, 256, 54912, stream>>>(y, w2p, w2b, out);
}

// Round 4
// 382.681 us; speedup vs baseline: 12.4042x; 3.3557x over previous
//
#include <hip/hip_runtime.h>
#include <hip/hip_bf16.h>

#define CC 96

typedef short short8  __attribute__((ext_vector_type(8)));
typedef short short4v __attribute__((ext_vector_type(4)));
typedef float f32x4   __attribute__((ext_vector_type(4)));

static __device__ __forceinline__ ushort f2bf(float f) {
  __hip_bfloat16 h = __float2bfloat16(f);
  return *reinterpret_cast<ushort*>(&h);
}
static __device__ __forceinline__ float bf2f(ushort u) {
  union { unsigned int u; float f; } v; v.u = ((unsigned int)u) << 16; return v.f;
}

// ---------------- prep: pack all weights ----------------
// qkvp [h][ks][nt][lane][8] bf16 (36864): B-frags for QKV GEMM
// projp [ks][nt][lane][8] bf16 (9216)
// w2p   conv3 B-frags bf16 (82944)
// w1p   [ks][12nt][lane][8] bf16 (18432): B-frags for conv1x1 (N=192)
__global__ void prep_kernel(const float* __restrict__ qkv_w,
                            const float* __restrict__ proj_w,
                            const float* __restrict__ w2w,
                            const float* __restrict__ w1w,
                            __hip_bfloat16* __restrict__ qkvp,
                            __hip_bfloat16* __restrict__ projp,
                            __hip_bfloat16* __restrict__ w2p,
                            __hip_bfloat16* __restrict__ w1p)
{
  const int i = blockIdx.x*256 + threadIdx.x;
  if (i < 36864) {
    const int e = i & 7, lane = (i >> 3) & 63;
    const int rest = i >> 9;           // (h*3+ks)*6+nt
    const int nt = rest % 6, r2 = rest / 6;
    const int ks = r2 % 3, h = r2 / 3;
    const int col = nt*16 + (lane & 15);
    const int sec = col >> 5, d = col & 31;
    const int c = ks*32 + (lane >> 4)*8 + e;
    const float val = (d < 24) ? qkv_w[(sec*96 + h*24 + d)*96 + c] : 0.f;
    qkvp[i] = __float2bfloat16(val);
  }
  const int j = i - 36864;
  if (j >= 0 && j < 9216) {
    const int e = j & 7, lane = (j >> 3) & 63;
    const int rest = j >> 9;           // ks*6+nt
    const int nt = rest % 6, ks = rest / 6;
    const int oc = nt*16 + (lane & 15);
    const int dd = ks*32 + (lane >> 4)*8 + e;
    projp[j] = __float2bfloat16(proj_w[oc*96 + dd]);
  }
  const int k = i - 46080;
  if (k >= 0 && k < 82944) {
    const int e = k & 7;
    const int lane = (k >> 3) & 63;
    const int rest = k >> 9;           // (tap*3+kc)*6+nf
    const int nf = rest % 6;
    const int r2 = rest / 6;
    const int kc = r2 % 3;
    const int tap = r2 / 3;
    const int cidx = kc*32 + (lane >> 4)*8 + e;
    const int oc = nf*16 + (lane & 15);
    const int ky = tap / 3, kx = tap - ky*3;
    w2p[k] = __float2bfloat16(w2w[((oc*96 + cidx)*3 + ky)*3 + kx]);
  }
  const int m = i - 129024;
  if (m >= 0 && m < 18432) {
    const int e = m & 7, lane = (m >> 3) & 63;
    const int rest = m >> 9;           // ks*12+nt
    const int nt = rest % 12, ks = rest / 12;
    const int oc = nt*16 + (lane & 15);        // 0..191
    const int c  = ks*32 + (lane >> 4)*8 + e;  // 0..95
    w1p[m] = __float2bfloat16(w1w[oc*96 + c]);
  }
}

// ---------------- Kernel 1: windowed MHA via MFMA + residual ----------------
__global__ __launch_bounds__(256, 2) void attn_kernel(
    const float* __restrict__ x,
    const float* __restrict__ norm_w,
    const __hip_bfloat16* __restrict__ qkvp,
    const float* __restrict__ qkv_b,
    const __hip_bfloat16* __restrict__ projp,
    const float* __restrict__ proj_b,
    const float* __restrict__ bias_table,
    float* __restrict__ out)
{
  extern __shared__ char smem[];
  ushort* xn   = (ushort*)smem;              // [64][104] bf16: xn, later o, later outT[96][68]
  float*  xf   = (float*)(smem + 13312);     // [64][97] f32 (phase 1 only)
  float*  btab = (float*)(smem + 64512);     // [225]

  const int wid = blockIdx.x;
  const int b  = wid >> 10;
  const int wy = (wid >> 5) & 31;
  const int wx = wid & 31;
  const int t  = threadIdx.x;
  const int y0 = wy*8, x0 = wx*8;
  const int l  = t & 63;
  const int w  = __builtin_amdgcn_readfirstlane(t >> 6);
  const int lr = l & 15, g = l >> 4;

  for (int i = t; i < 225; i += 256) btab[i] = bias_table[i];

  for (int e = t; e < 1536; e += 256) {
    const int c = e >> 4, q4 = e & 15;
    const int ty = q4 >> 1, tx0 = (q4 & 1) << 2;
    const float4 v = *(const float4*)(x + (size_t)(b*CC+c)*65536 + (size_t)(y0+ty)*256 + x0 + tx0);
    const int n = ty*8 + tx0;
    xf[(n+0)*97+c] = v.x; xf[(n+1)*97+c] = v.y; xf[(n+2)*97+c] = v.z; xf[(n+3)*97+c] = v.w;
  }
  __syncthreads();

  {
    const int n = t >> 2, c0 = (t & 3) * 24;
    float ss = 0.f;
    #pragma unroll
    for (int i = 0; i < 24; i++) { const float u = xf[n*97 + c0 + i]; ss += u*u; }
    ss += __shfl_xor(ss, 1);
    ss += __shfl_xor(ss, 2);
    const float s = rsqrtf(ss * (1.f/96.f) + 1e-6f);
    #pragma unroll
    for (int i = 0; i < 24; i++) {
      const int c = c0 + i;
      xn[n*104 + c] = f2bf(xf[n*97+c] * s * norm_w[c]);
    }
  }
  __syncthreads();

  const int h = w;
  char* hbase = smem + 13312 + h*12800;
  ushort* Qs = (ushort*)hbase;               // [64][32] bf16
  ushort* Ks = (ushort*)(hbase + 4096);      // [64][32]
  ushort* Vt = (ushort*)(hbase + 8192);      // [32][72]
  ushort* Ps = (ushort*)hbase;               // [64][64] swizzled, overlays Q+K

  f32x4 acc[4][6];
  #pragma unroll
  for (int mt = 0; mt < 4; mt++)
    #pragma unroll
    for (int nt = 0; nt < 6; nt++) acc[mt][nt] = (f32x4)0.f;

  #pragma unroll
  for (int ks = 0; ks < 3; ks++) {
    short8 afr[4];
    #pragma unroll
    for (int mt = 0; mt < 4; mt++)
      afr[mt] = *(const short8*)((const char*)xn + (lr + mt*16)*208 + g*16 + ks*64);
    #pragma unroll
    for (int nt = 0; nt < 6; nt++) {
      const short8 bfr = *(const short8*)(qkvp + ((h*3+ks)*6+nt)*512 + l*8);
      #pragma unroll
      for (int mt = 0; mt < 4; mt++)
        acc[mt][nt] = __builtin_amdgcn_mfma_f32_16x16x32_bf16(afr[mt], bfr, acc[mt][nt], 0, 0, 0);
    }
  }
  __syncthreads();

  #pragma unroll
  for (int nt = 0; nt < 4; nt++) {
    const int sec  = nt >> 1;
    const int dcol = lr + (nt & 1)*16;
    ushort* dst = sec ? Ks : Qs;
    const float bias = (dcol < 24) ? qkv_b[sec*96 + h*24 + dcol] : 0.f;
    #pragma unroll
    for (int mt = 0; mt < 4; mt++)
      #pragma unroll
      for (int r = 0; r < 4; r++) {
        const int row = g*4 + r + mt*16;
        const float val = (dcol < 24) ? (acc[mt][nt][r] + bias) : 0.f;
        dst[row*32 + dcol] = f2bf(val);
      }
  }
  #pragma unroll
  for (int nt = 4; nt < 6; nt++) {
    const int vd = lr + (nt-4)*16;
    const float bias = (vd < 24) ? qkv_b[192 + h*24 + vd] : 0.f;
    #pragma unroll
    for (int mt = 0; mt < 4; mt++) {
      short4v pk;
      #pragma unroll
      for (int r = 0; r < 4; r++) {
        const float val = (vd < 24) ? (acc[mt][nt][r] + bias) : 0.f;
        pk[r] = (short)f2bf(val);
      }
      *(short4v*)((char*)Vt + vd*144 + (g*4 + mt*16)*2) = pk;
    }
  }

  f32x4 sacc[4][4];
  {
    short8 qf[4], kf[4];
    #pragma unroll
    for (int mt = 0; mt < 4; mt++) qf[mt] = *(const short8*)((char*)Qs + (lr+mt*16)*64 + g*16);
    #pragma unroll
    for (int nt = 0; nt < 4; nt++) kf[nt] = *(const short8*)((char*)Ks + (lr+nt*16)*64 + g*16);
    #pragma unroll
    for (int mt = 0; mt < 4; mt++)
      #pragma unroll
      for (int nt = 0; nt < 4; nt++)
        sacc[mt][nt] = __builtin_amdgcn_mfma_f32_16x16x32_bf16(qf[mt], kf[nt], (f32x4)0.f, 0, 0, 0);
  }

  {
    const float SCALE = 0.20412414523193154f;
    int bk[4];
    #pragma unroll
    for (int nt = 0; nt < 4; nt++) {
      const int k = lr + nt*16;
      bk[nt] = 112 - ((k >> 3)*15 + (k & 7));
    }
    #pragma unroll
    for (int mt = 0; mt < 4; mt++)
      #pragma unroll
      for (int r = 0; r < 4; r++) {
        const int q  = g*4 + r + mt*16;
        const int aq = (q >> 3)*15 + (q & 7);
        float v[4];
        #pragma unroll
        for (int nt = 0; nt < 4; nt++) v[nt] = sacc[mt][nt][r]*SCALE + btab[aq + bk[nt]];
        float mx = fmaxf(fmaxf(v[0], v[1]), fmaxf(v[2], v[3]));
        mx = fmaxf(mx, __shfl_xor(mx, 1));
        mx = fmaxf(mx, __shfl_xor(mx, 2));
        mx = fmaxf(mx, __shfl_xor(mx, 4));
        mx = fmaxf(mx, __shfl_xor(mx, 8));
        float e[4], s = 0.f;
        #pragma unroll
        for (int nt = 0; nt < 4; nt++) { e[nt] = __expf(v[nt]-mx); s += e[nt]; }
        s += __shfl_xor(s, 1); s += __shfl_xor(s, 2);
        s += __shfl_xor(s, 4); s += __shfl_xor(s, 8);
        const float rinv = 1.0f / s;
        const int sw = (q & 7) << 4;
        #pragma unroll
        for (int nt = 0; nt < 4; nt++) {
          const int kk = (lr + nt*16)*2;
          *(ushort*)((char*)Ps + q*128 + (kk ^ sw)) = f2bf(e[nt]*rinv);
        }
      }
  }

  {
    f32x4 oacc[4][2];
    #pragma unroll
    for (int mt = 0; mt < 4; mt++) { oacc[mt][0] = (f32x4)0.f; oacc[mt][1] = (f32x4)0.f; }
    #pragma unroll
    for (int ks = 0; ks < 2; ks++) {
      short8 pf[4], vf[2];
      #pragma unroll
      for (int mt = 0; mt < 4; mt++) {
        const int row = lr + mt*16;
        pf[mt] = *(const short8*)((char*)Ps + row*128 + ((g*16 + ks*64) ^ ((row & 7) << 4)));
      }
      #pragma unroll
      for (int nt = 0; nt < 2; nt++)
        vf[nt] = *(const short8*)((char*)Vt + (lr+nt*16)*144 + g*16 + ks*64);
      #pragma unroll
      for (int mt = 0; mt < 4; mt++)
        #pragma unroll
        for (int nt = 0; nt < 2; nt++)
          oacc[mt][nt] = __builtin_amdgcn_mfma_f32_16x16x32_bf16(pf[mt], vf[nt], oacc[mt][nt], 0, 0, 0);
    }
    ushort* oM = xn;
    #pragma unroll
    for (int nt = 0; nt < 2; nt++) {
      const int d0 = lr + nt*16;
      if (d0 < 24) {
        #pragma unroll
        for (int mt = 0; mt < 4; mt++)
          #pragma unroll
          for (int r = 0; r < 4; r++) {
            const int row = g*4 + r + mt*16;
            oM[row*104 + h*24 + d0] = f2bf(oacc[mt][nt][r]);
          }
      }
    }
  }
  __syncthreads();

  {
    f32x4 pacc[6];
    #pragma unroll
    for (int nt = 0; nt < 6; nt++) pacc[nt] = (f32x4)0.f;
    #pragma unroll
    for (int ks = 0; ks < 3; ks++) {
      const short8 af = *(const short8*)((const char*)xn + (lr + w*16)*208 + g*16 + ks*64);
      #pragma unroll
      for (int nt = 0; nt < 6; nt++) {
        const short8 bf = *(const short8*)(projp + (ks*6+nt)*512 + l*8);
        pacc[nt] = __builtin_amdgcn_mfma_f32_16x16x32_bf16(af, bf, pacc[nt], 0, 0, 0);
      }
    }
    __syncthreads();
    ushort* oT = xn;
    #pragma unroll
    for (int nt = 0; nt < 6; nt++) {
      const int oc = lr + nt*16;
      const float bias = proj_b[oc];
      short4v pk;
      #pragma unroll
      for (int r = 0; r < 4; r++) pk[r] = (short)f2bf(pacc[nt][r] + bias);
      *(short4v*)((char*)oT + oc*136 + (g*4 + w*16)*2) = pk;
    }
  }
  __syncthreads();

  {
    const ushort* oT = xn;
    #pragma unroll
    for (int k2 = 0; k2 < 6; k2++) {
      const int v = t + k2*256;
      const int oc = v >> 4, pq = v & 15;
      const int ty = pq >> 1, tx4 = (pq & 1) << 2;
      const int pl = ty*8 + tx4;
      const short4v ov = *(const short4v*)((const char*)oT + oc*136 + pl*2);
      const size_t gidx = (size_t)(b*CC+oc)*65536 + (size_t)(y0+ty)*256 + x0 + tx4;
      float4 xv = *(const float4*)(x + gidx);
      float4 res;
      res.x = xv.x + bf2f((ushort)ov[0]);
      res.y = xv.y + bf2f((ushort)ov[1]);
      res.z = xv.z + bf2f((ushort)ov[2]);
      res.w = xv.w + bf2f((ushort)ov[3]);
      *(float4*)(out + gidx) = res;
    }
  }
}

// ---------------- Kernel 2: RMSNorm + conv1x1 + GLU via MFMA -> y bf16 [b][hw][96] ----------------
// block = 256 thr / 128 px. GEMM [128 x 96] @ [96 x 192], GLU epilogue.
__global__ __launch_bounds__(256, 2) void mlp1_kernel(
    const float* __restrict__ x1,
    const float* __restrict__ mlp_norm_w,
    const __hip_bfloat16* __restrict__ w1p,   // [ks][12][64][8]
    const float* __restrict__ w1_b,
    __hip_bfloat16* __restrict__ y)           // [b][hw][96]
{
  __shared__ ushort xn[128*104];               // A-tile, reused as y-tile
  const int blk = blockIdx.x;
  const int b   = blk >> 9;
  const int p0  = (blk & 511) << 7;
  const int t   = threadIdx.x;
  const int l   = t & 63;
  const int w   = __builtin_amdgcn_readfirstlane(t >> 6);
  const int lr  = l & 15, g = l >> 4;

  // ---- phase 1: load (coalesced dword) + RMSNorm -> xn bf16; wave-private rows ----
  {
    const int p = t >> 1, half = t & 1;
    const float* xp = x1 + (size_t)(b*CC + half*48)*65536 + p0 + p;
    float xv[48];
    float ss = 0.f;
    #pragma unroll
    for (int i = 0; i < 48; i++) { xv[i] = xp[(size_t)i*65536]; ss += xv[i]*xv[i]; }
    ss += __shfl_xor(ss, 1);
    const float s = rsqrtf(ss*(1.f/96.f) + 1e-6f);
    #pragma unroll
    for (int i = 0; i < 48; i += 2) {
      const int c = half*48 + i;
      union { ushort u[2]; uint v; } pk;
      pk.u[0] = f2bf(xv[i]   * s * mlp_norm_w[c]);
      pk.u[1] = f2bf(xv[i+1] * s * mlp_norm_w[c+1]);
      *(uint*)(&xn[p*104 + c]) = pk.v;
    }
  }
  // wave w wrote rows w*32..w*32+31 and reads only those rows below ->
  // same-wave LDS ordering (compiler lgkmcnt) suffices; no barrier.

  // ---- phase 2: GEMM, wave w owns mtiles {2w, 2w+1}, 12 ntiles ----
  f32x4 acc[2][12];
  #pragma unroll
  for (int m2 = 0; m2 < 2; m2++)
    #pragma unroll
    for (int nt = 0; nt < 12; nt++) acc[m2][nt] = (f32x4)0.f;

  #pragma unroll
  for (int ks = 0; ks < 3; ks++) {
    short8 afr[2];
    #pragma unroll
    for (int m2 = 0; m2 < 2; m2++)
      afr[m2] = *(const short8*)((const char*)xn + (lr + (w*2+m2)*16)*208 + g*16 + ks*64);
    #pragma unroll
    for (int nt = 0; nt < 12; nt++) {
      const short8 bfr = *(const short8*)(w1p + ((ks*12+nt)*64 + l)*8);
      #pragma unroll
      for (int m2 = 0; m2 < 2; m2++)
        acc[m2][nt] = __builtin_amdgcn_mfma_f32_16x16x32_bf16(afr[m2], bfr, acc[m2][nt], 0, 0, 0);
    }
  }

  // ---- phase 3: GLU -> bf16 into xn (wave-private rows again) ----
  #pragma unroll
  for (int m2 = 0; m2 < 2; m2++)
    #pragma unroll
    for (int nt = 0; nt < 6; nt++) {
      const int oc = nt*16 + lr;
      const float ab = w1_b[oc], gb = w1_b[96+oc];
      #pragma unroll
      for (int r = 0; r < 4; r++) {
        const int row = (w*2+m2)*16 + g*4 + r;
        const float a  = acc[m2][nt][r]   + ab;
        const float gg = acc[m2][nt+6][r] + gb;
        xn[row*104 + oc] = f2bf(a / (1.f + __expf(-gg)));
      }
    }
  __syncthreads();

  // ---- phase 4: coalesced short8 stores ----
  __hip_bfloat16* yp = y + ((size_t)(b*65536 + p0))*96;
  #pragma unroll
  for (int k2 = 0; k2 < 6; k2++) {
    const int e = t + k2*256;
    const int p = e / 12, ch = e - p*12;
    const short8 v = *(const short8*)(&xn[p*104 + ch*8]);
    *(short8*)((ushort*)yp + p*96 + ch*8) = v;
  }
}

// ---------------- Kernel 3: conv3x3 via MFMA implicit GEMM + leaky + residual ----------------
__global__ __launch_bounds__(256) void conv3_kernel(
    const __hip_bfloat16* __restrict__ y,    // [b][hw][96]
    const __hip_bfloat16* __restrict__ w2p,  // packed fragments
    const float* __restrict__ w2_b,
    float* __restrict__ xout)
{
  extern __shared__ char smem[];
  ushort* A = (ushort*)smem;
  float*  O = (float*)smem;

  const int bid = blockIdx.x;
  const int b   = bid >> 9;
  const int rp  = (bid >> 2) & 127;
  const int ch  = bid & 3;
  const int px0 = ch << 6;
  const int t   = threadIdx.x;
  const int w   = __builtin_amdgcn_readfirstlane(t >> 6);
  const int l   = t & 63;
  const int m15 = l & 15, lh = l >> 4;

  for (int e = t; e < 3168; e += 256) {
    const int seg  = e / 12;
    const int part = e - seg*12;
    const int ky = seg / 66;
    const int px = seg - ky*66;
    const int gy = min(255, max(0, 2*rp + ky - 1));
    const int gx = min(255, max(0, px0 + px - 1));
    const short8 v = *(const short8*)(y + ((size_t)(b*65536 + gy*256 + gx))*96 + part*8);
    *(short8*)(A + seg*104 + part*8) = v;
  }
  __syncthreads();

  f32x4 acc0[6], acc1[6];
  #pragma unroll
  for (int nf = 0; nf < 6; ++nf) { acc0[nf] = (f32x4)0.f; acc1[nf] = (f32x4)0.f; }

  for (int tap = 0; tap < 9; ++tap) {
    const int ky = tap / 3, kx = tap - ky*3;
    for (int kc = 0; kc < 3; ++kc) {
      const int cb = kc*32 + lh*8;
      const short8 a0 = *(const short8*)(A + ((ky  )*66 + 16*w + m15 + kx)*104 + cb);
      const short8 a1 = *(const short8*)(A + ((ky+1)*66 + 16*w + m15 + kx)*104 + cb);
      const short8* bp = (const short8*)w2p + ((size_t)(tap*3 + kc)*6)*64 + l;
      #pragma unroll
      for (int nf = 0; nf < 6; ++nf) {
        const short8 bf = bp[nf*64];
        acc0[nf] = __builtin_amdgcn_mfma_f32_16x16x32_bf16(a0, bf, acc0[nf], 0, 0, 0);
        acc1[nf] = __builtin_amdgcn_mfma_f32_16x16x32_bf16(a1, bf, acc1[nf], 0, 0, 0);
      }
    }
  }
  __syncthreads();

  {
    const int jb = 16*w + lh*4;
    #pragma unroll
    for (int nf = 0; nf < 6; ++nf) {
      const int oc = nf*16 + m15;
      *(f32x4*)(O + oc*132 + jb)      = acc0[nf];
      *(f32x4*)(O + oc*132 + 64 + jb) = acc1[nf];
    }
  }
  __syncthreads();

  for (int e = t; e < 3072; e += 256) {
    const int oc = e >> 5;
    const int j  = (e & 31) * 4;
    f32x4 v = *(const f32x4*)(O + oc*132 + j);
    const float bb = w2_b[oc];
    const int gy = 2*rp + (j >> 6);
    const int px = px0 + (j & 63);
    float* op = xout + ((size_t)(b*CC + oc))*65536 + (size_t)gy*256 + px;
    f32x4 r = *(const f32x4*)op;
    #pragma unroll
    for (int q = 0; q < 4; ++q) {
      float u = v[q] + bb;
      u = (u >= 0.f) ? u : 0.1f*u;
      r[q] += u;
    }
    *(f32x4*)op = r;
  }
}

extern "C" void kernel_launch(void* const* d_in, const int* in_sizes, int n_in,
                              void* d_out, int out_size, void* d_ws, size_t ws_size,
                              hipStream_t stream)
{
  (void)in_sizes; (void)n_in; (void)out_size; (void)ws_size;
  const float* x      = (const float*)d_in[0];
  const float* norm_w = (const float*)d_in[1];
  const float* qkv_w  = (const float*)d_in[2];
  const float* qkv_b  = (const float*)d_in[3];
  const float* proj_w = (const float*)d_in[4];
  const float* proj_b = (const float*)d_in[5];
  const float* btab   = (const float*)d_in[6];
  const float* mlpnw  = (const float*)d_in[7];
  const float* w1w    = (const float*)d_in[8];
  const float* w1b    = (const float*)d_in[9];
  const float* w2w    = (const float*)d_in[10];
  const float* w2b    = (const float*)d_in[11];
  float* out = (float*)d_out;

  char* ws = (char*)d_ws;
  __hip_bfloat16* y     = (__hip_bfloat16*)ws;                    // 50,331,648 B
  __hip_bfloat16* w2p   = (__hip_bfloat16*)(ws + 50331648);       // 165,888 B
  __hip_bfloat16* qkvp  = (__hip_bfloat16*)(ws + 50497536);       // 73,728 B
  __hip_bfloat16* projp = (__hip_bfloat16*)(ws + 50571264);       // 18,432 B
  __hip_bfloat16* w1p   = (__hip_bfloat16*)(ws + 50589696);       // 36,864 B

  prep_kernel<<<576, 256, 0, stream>>>(qkv_w, proj_w, w2w, w1w, qkvp, projp, w2p, w1p);

  attn_kernel<<<4096, 256, 65412, stream>>>(x, norm_w, qkvp, qkv_b, projp, proj_b, btab, out);
  mlp1_kernel<<<2048, 256, 0, stream>>>(out, mlpnw, w1p, w1b, y);
  conv3_kernel<<<2048, 256, 54912, stream>>>(y, w2p, w2b, out);
}